// Round 5
// baseline (299.206 us; speedup 1.0000x reference)
//
#include <hip/hip_runtime.h>
#include <math.h>

#define BATCH_N 16384

// ---------------------------------------------------------------------------
// Fully fused: conv1+pool -> conv2+pool -> fc1+relu -> fc2+sigmoid -> circuit
// -> classifier. Block = 8 samples, 256 threads. All intermediates in LDS.
//
// LDS float-offset map (union across phases; 13392 floats = 53568 B):
//   phase A : XS[0..6272)  H1S[6272..13184)  WT[13184..13384) BS1[13384..13392)
//   phase B : W2S[0..2400) B2S[2400..2416)  H2S[2416..4976)   H1S live
//   phase C : HS[0..992)   FC2W[1000..1484) H2S live          W1C[4992..13152)
//   phase D : ANG[1500..1532)
// ---------------------------------------------------------------------------
#define XS    0
#define H1S   6272
#define W2S   0
#define B2S   2400
#define H2S   2416     // [s][oc*20 + pos], 8 x 320
#define W1C   4992     // [n][j], 120 x 68 (stride 68: 16B-aligned, bank-clean)
#define HS    0        // [s][n], 8 x 124
#define FC2W  1000     // 480 w + 4 b
#define ANG   1500
#define WT    13184    // conv1 weights transposed [k][8]
#define BS1   13384
#define LDS_FLOATS 13392

__global__ __launch_bounds__(256, 2) void fused_model(
    const float* __restrict__ xg,
    const float* __restrict__ c1w, const float* __restrict__ c1b,
    const float* __restrict__ c2w, const float* __restrict__ c2b,
    const float* __restrict__ f1w, const float* __restrict__ f1b,
    const float* __restrict__ f2w, const float* __restrict__ f2b,
    const float* __restrict__ qw,  const float* __restrict__ cw,
    const float* __restrict__ cbias, float* __restrict__ out) {
    __shared__ float L[LDS_FLOATS];
    const int tid = threadIdx.x;
    const int b0 = blockIdx.x * 8;

    // ================= phase A: load x + conv1 weights =================
    for (int i = tid; i < 1568; i += 256)
        ((float4*)(L + XS))[i] = ((const float4*)(xg + (size_t)b0 * 784))[i];
    if (tid < 150) L[WT + (tid % 25) * 8 + tid / 25] = c1w[tid];  // slots 6,7 unread
    if (tid < 6) L[BS1 + tid] = c1b[tid];
    __syncthreads();

    // conv1 + relu + pool: 8 samples x 144 pooled positions = 1152 tasks
    for (int t = tid; t < 1152; t += 256) {
        const int s = t / 144;
        const int r = t - s * 144;
        const int py = r / 12, px = r - (r / 12) * 12;
        const float* xp = L + XS + s * 784 + (2 * py) * 28 + 2 * px;

        float p[6][6];
#pragma unroll
        for (int rr = 0; rr < 6; rr++) {
            float2 u = *(const float2*)(xp + rr * 28);
            float2 v = *(const float2*)(xp + rr * 28 + 2);
            float2 w = *(const float2*)(xp + rr * 28 + 4);
            p[rr][0] = u.x; p[rr][1] = u.y; p[rr][2] = v.x;
            p[rr][3] = v.y; p[rr][4] = w.x; p[rr][5] = w.y;
        }

        float acc[6][4];
#pragma unroll
        for (int o = 0; o < 6; o++) {
            const float bv = L[BS1 + o];
            acc[o][0] = bv; acc[o][1] = bv; acc[o][2] = bv; acc[o][3] = bv;
        }

#pragma unroll
        for (int ky = 0; ky < 5; ky++)
#pragma unroll
            for (int kx = 0; kx < 5; kx++) {
                const int k = ky * 5 + kx;
                const float4 wA = *(const float4*)&L[WT + k * 8];
                const float2 wB = *(const float2*)&L[WT + k * 8 + 4];
                const float p00 = p[ky][kx],     p01 = p[ky][kx + 1];
                const float p10 = p[ky + 1][kx], p11 = p[ky + 1][kx + 1];
                acc[0][0] = fmaf(wA.x, p00, acc[0][0]); acc[0][1] = fmaf(wA.x, p01, acc[0][1]);
                acc[0][2] = fmaf(wA.x, p10, acc[0][2]); acc[0][3] = fmaf(wA.x, p11, acc[0][3]);
                acc[1][0] = fmaf(wA.y, p00, acc[1][0]); acc[1][1] = fmaf(wA.y, p01, acc[1][1]);
                acc[1][2] = fmaf(wA.y, p10, acc[1][2]); acc[1][3] = fmaf(wA.y, p11, acc[1][3]);
                acc[2][0] = fmaf(wA.z, p00, acc[2][0]); acc[2][1] = fmaf(wA.z, p01, acc[2][1]);
                acc[2][2] = fmaf(wA.z, p10, acc[2][2]); acc[2][3] = fmaf(wA.z, p11, acc[2][3]);
                acc[3][0] = fmaf(wA.w, p00, acc[3][0]); acc[3][1] = fmaf(wA.w, p01, acc[3][1]);
                acc[3][2] = fmaf(wA.w, p10, acc[3][2]); acc[3][3] = fmaf(wA.w, p11, acc[3][3]);
                acc[4][0] = fmaf(wB.x, p00, acc[4][0]); acc[4][1] = fmaf(wB.x, p01, acc[4][1]);
                acc[4][2] = fmaf(wB.x, p10, acc[4][2]); acc[4][3] = fmaf(wB.x, p11, acc[4][3]);
                acc[5][0] = fmaf(wB.y, p00, acc[5][0]); acc[5][1] = fmaf(wB.y, p01, acc[5][1]);
                acc[5][2] = fmaf(wB.y, p10, acc[5][2]); acc[5][3] = fmaf(wB.y, p11, acc[5][3]);
            }

        float* op = L + H1S + s * 864 + py * 12 + px;
#pragma unroll
        for (int o = 0; o < 6; o++) {
            const float m = fmaxf(fmaxf(acc[o][0], acc[o][1]), fmaxf(acc[o][2], acc[o][3]));
            op[o * 144] = fmaxf(m, 0.f);
        }
    }
    __syncthreads();

    // ================= phase B: conv2 + relu + pool =================
    for (int i = tid; i < 600; i += 256)
        ((float4*)(L + W2S))[i] = ((const float4*)c2w)[i];
    if (tid < 16) L[B2S + tid] = c2b[tid];
    __syncthreads();

#pragma unroll
    for (int it = 0; it < 2; it++) {
        const int task = tid + it * 256;
        const int s = task >> 6;
        const int lane = task & 63;
        const int oc = lane & 15;
        const int quad = lane >> 4;
        const int qy = quad >> 1, qx = quad & 1;

        float acc[4][4];
        {
            const float bv = L[B2S + oc];
#pragma unroll
            for (int dy = 0; dy < 4; dy++)
#pragma unroll
                for (int dx = 0; dx < 4; dx++) acc[dy][dx] = bv;
        }

        for (int ic = 0; ic < 6; ic++) {
            const float* xp = L + H1S + s * 864 + ic * 144 + (4 * qy) * 12 + 4 * qx;
            float p[8][8];
#pragma unroll
            for (int r = 0; r < 8; r++) {
                float4 u = *(const float4*)(xp + r * 12);
                float4 v = *(const float4*)(xp + r * 12 + 4);
                p[r][0] = u.x; p[r][1] = u.y; p[r][2] = u.z; p[r][3] = u.w;
                p[r][4] = v.x; p[r][5] = v.y; p[r][6] = v.z; p[r][7] = v.w;
            }
            const float* wp = L + W2S + (oc * 6 + ic) * 25;
#pragma unroll
            for (int ky = 0; ky < 5; ky++)
#pragma unroll
                for (int kx = 0; kx < 5; kx++) {
                    const float wv = wp[ky * 5 + kx];
#pragma unroll
                    for (int dy = 0; dy < 4; dy++)
#pragma unroll
                        for (int dx = 0; dx < 4; dx++)
                            acc[dy][dx] = fmaf(wv, p[ky + dy][kx + dx], acc[dy][dx]);
                }
        }

#pragma unroll
        for (int i = 0; i < 2; i++)
#pragma unroll
            for (int j = 0; j < 2; j++) {
                const float m = fmaxf(fmaxf(acc[2 * i][2 * j],     acc[2 * i][2 * j + 1]),
                                      fmaxf(acc[2 * i + 1][2 * j], acc[2 * i + 1][2 * j + 1]));
                L[H2S + s * 320 + oc * 20 + (2 * qy + i) * 4 + (2 * qx + j)] = fmaxf(m, 0.f);
            }
    }
    __syncthreads();

    // ================= phase C: fc1 (256->120) + relu, fc2 (120->4) ========
    // stage fc2 weights/bias (region was W2S, now dead)
    for (int i = tid; i < 480; i += 256) L[FC2W + i] = f2w[i];
    if (tid < 4) L[FC2W + 480 + tid] = f2b[tid];

    const int g = tid / 120;          // 0,1 active; 2 idle (tid 240..255)
    const int n = tid - g * 120;
    float facc[4] = {0.f, 0.f, 0.f, 0.f};

    for (int kc = 0; kc < 4; kc++) {
        // stage w1[:, kc*64 : kc*64+64] -> W1C[n*68 + j], coalesced float4
        for (int i = tid; i < 1920; i += 256) {
            const int nn = i >> 4, jj4 = i & 15;
            *(float4*)&L[W1C + nn * 68 + jj4 * 4] =
                ((const float4*)(f1w + (size_t)nn * 256 + kc * 64))[jj4];
        }
        __syncthreads();
        if (g < 2) {
#pragma unroll
            for (int j = 0; j < 64; j += 4) {
                const float4 wv = *(const float4*)&L[W1C + n * 68 + j];
                const int k = kc * 64 + j;
                const int row = (k >> 4) * 20 + (k & 15);
#pragma unroll
                for (int i = 0; i < 4; i++) {
                    const float4 hv = *(const float4*)&L[H2S + (g * 4 + i) * 320 + row];
                    facc[i] = fmaf(wv.x, hv.x, facc[i]);
                    facc[i] = fmaf(wv.y, hv.y, facc[i]);
                    facc[i] = fmaf(wv.z, hv.z, facc[i]);
                    facc[i] = fmaf(wv.w, hv.w, facc[i]);
                }
            }
        }
        __syncthreads();
    }

    if (g < 2) {
        const float bv = f1b[n];
#pragma unroll
        for (int i = 0; i < 4; i++)
            L[HS + (g * 4 + i) * 124 + n] = fmaxf(facc[i] + bv, 0.f);
    }
    __syncthreads();

    // fc2 + pi*sigmoid: 8 samples x 4 feats = 32 tasks
    if (tid < 32) {
        const int s = tid >> 2, m = tid & 3;
        float f = L[FC2W + 480 + m];
#pragma unroll
        for (int nn = 0; nn < 120; nn += 4) {
            const float4 wv = *(const float4*)&L[FC2W + m * 120 + nn];
            const float4 hv = *(const float4*)&L[HS + s * 124 + nn];
            f = fmaf(wv.x, hv.x, f);
            f = fmaf(wv.y, hv.y, f);
            f = fmaf(wv.z, hv.z, f);
            f = fmaf(wv.w, hv.w, f);
        }
        L[ANG + s * 4 + m] = 3.14159265358979323846f / (1.f + expf(-f));
    }
    __syncthreads();

    // ================= phase D: quantum circuit + classifier =================
    if (tid < 8) {
        const int s = tid;
        const float av[4] = {L[ANG + s * 4 + 0], L[ANG + s * 4 + 1],
                             L[ANG + s * 4 + 2], L[ANG + s * 4 + 3]};
        float sr[16], si[16];
#pragma unroll
        for (int i = 0; i < 16; i++) { sr[i] = 0.f; si[i] = 0.f; }
        sr[0] = 1.f;

#pragma unroll
        for (int l = 0; l < 3; l++) {
#pragma unroll
            for (int w = 0; w < 4; w++) {
                const float phi = qw[(l * 4 + w) * 3 + 0];
                const float th  = qw[(l * 4 + w) * 3 + 1];
                const float om  = qw[(l * 4 + w) * 3 + 2];
                const float ct = cosf(0.5f * th), st = sinf(0.5f * th);
                const float ap = 0.5f * (phi + om), bm = 0.5f * (phi - om);
                const float ca = cosf(ap), sa = sinf(ap);
                const float cbm = cosf(bm), sbm = sinf(bm);
                const float m00r =  ct * ca,  m00i = -ct * sa;
                const float m01r = -st * cbm, m01i = -st * sbm;
                const float m10r =  st * cbm, m10i = -st * sbm;
                const float m11r =  ct * ca,  m11i =  ct * sa;
                const int mask = 8 >> w;
#pragma unroll
                for (int i = 0; i < 16; i++)
                    if (!(i & mask)) {
                        const int j = i | mask;
                        const float xr = sr[i], xi = si[i], yr = sr[j], yi = si[j];
                        sr[i] = m00r * xr - m00i * xi + m01r * yr - m01i * yi;
                        si[i] = m00r * xi + m00i * xr + m01r * yi + m01i * yr;
                        sr[j] = m10r * xr - m10i * xi + m11r * yr - m11i * yi;
                        si[j] = m10r * xi + m10i * xr + m11r * yi + m11i * yr;
                    }
            }
#pragma unroll
            for (int w = 0; w < 4; w++) {
                const int mc = 8 >> w, mt = 8 >> ((w + 1) & 3);
#pragma unroll
                for (int i = 0; i < 16; i++)
                    if ((i & mc) && !(i & mt)) {
                        const int j = i | mt;
                        const float tr = sr[i], ti = si[i];
                        sr[i] = sr[j]; si[i] = si[j];
                        sr[j] = tr;    si[j] = ti;
                    }
            }
#pragma unroll
            for (int w = 0; w < 4; w++) {
                const float c = cosf(0.5f * av[w]), s2 = sinf(0.5f * av[w]);
                const int mask = 8 >> w;
#pragma unroll
                for (int i = 0; i < 16; i++)
                    if (!(i & mask)) {
                        const int j = i | mask;
                        const float xr = sr[i], xi = si[i], yr = sr[j], yi = si[j];
                        sr[i] = c * xr + s2 * yi;
                        si[i] = c * xi - s2 * yr;
                        sr[j] = c * yr + s2 * xi;
                        si[j] = c * yi - s2 * xr;
                    }
            }
        }

        float z[4];
#pragma unroll
        for (int w = 0; w < 4; w++) {
            const int mask = 8 >> w;
            float zacc = 0.f;
#pragma unroll
            for (int i = 0; i < 16; i++) {
                const float pv = sr[i] * sr[i] + si[i] * si[i];
                zacc += (i & mask) ? -pv : pv;
            }
            z[w] = zacc;
        }
#pragma unroll
        for (int c = 0; c < 10; c++) {
            float v = cbias[c];
#pragma unroll
            for (int w = 0; w < 4; w++) v = fmaf(cw[c * 4 + w], z[w], v);
            out[(size_t)(b0 + s) * 10 + c] = v;
        }
    }
}

// ---------------------------------------------------------------------------
extern "C" void kernel_launch(void* const* d_in, const int* in_sizes, int n_in,
                              void* d_out, int out_size, void* d_ws, size_t ws_size,
                              hipStream_t stream) {
    const float* x   = (const float*)d_in[0];
    const float* c1w = (const float*)d_in[1];
    const float* c1b = (const float*)d_in[2];
    const float* c2w = (const float*)d_in[3];
    const float* c2b = (const float*)d_in[4];
    const float* f1w = (const float*)d_in[5];
    const float* f1b = (const float*)d_in[6];
    const float* f2w = (const float*)d_in[7];
    const float* f2b = (const float*)d_in[8];
    const float* qw  = (const float*)d_in[9];
    const float* cw  = (const float*)d_in[10];
    const float* cb  = (const float*)d_in[11];
    float* out = (float*)d_out;

    fused_model<<<BATCH_N / 8, 256, 0, stream>>>(x, c1w, c1b, c2w, c2b,
                                                 f1w, f1b, f2w, f2b,
                                                 qw, cw, cb, out);
}

// Round 6
// 268.266 us; speedup vs baseline: 1.1153x; 1.1153x over previous
//
#include <hip/hip_runtime.h>
#include <math.h>

#define BATCH_N 16384

typedef _Float16 half8 __attribute__((ext_vector_type(8)));
typedef float f32x4 __attribute__((ext_vector_type(4)));
union AU { unsigned int w[4]; half8 h; };

// ---------------------------------------------------------------------------
// LDS float-index map (L = 15632 floats = 62528 B; regions overlaid by phase):
//  [0,6272)      XS      x staging, fp32              (phase A)
//  [0,8160)      W1C     fc1 weight chunk, fp32       (phase C)
//  [8160,11616)  H1B     h1 as f16 (6912 halves)      (A out, B in)
//  [8160,9152)   HS      fc1 activations, fp32        (phase C out)
//  [9152,9636)   FC2W    fc2 w+b                      (phase C)
//  [9636,9668)   ANG     angles                       (phase D)
//  [11616,11824) WT/BS1  conv1 weights (fp32)         (phase A)
//  [11616,12896) W2H     conv2 weights f16 [16][160]  (phase B)
//  [12896,13056) OFF     k->h1 offset table, int      (phase B)
//  [13056,15616) H2S     h2 fp32 [s][oc*20+pos]       (B out, C in)
//  [15616,15632) BS2     conv2 bias fp32              (phase B)
// ---------------------------------------------------------------------------
#define XS_F    0
#define W1C_F   0
#define H1B_F   8160
#define HS_F    8160
#define FC2W_F  9152
#define ANG_F   9636
#define WT_F    11616
#define BS1_F   11816
#define OFF_F   12896
#define H2S_F   13056
#define BS2_F   15616
#define LDS_FLOATS 15632

__global__ __launch_bounds__(256, 2) void fused_model(
    const float* __restrict__ xg,
    const float* __restrict__ c1w, const float* __restrict__ c1b,
    const float* __restrict__ c2w, const float* __restrict__ c2b,
    const float* __restrict__ f1w, const float* __restrict__ f1b,
    const float* __restrict__ f2w, const float* __restrict__ f2b,
    const float* __restrict__ qw,  const float* __restrict__ cw,
    const float* __restrict__ cbias, float* __restrict__ out) {
    __shared__ float L[LDS_FLOATS];
    _Float16* H1H = (_Float16*)(L + H1B_F);
    const unsigned short* H1U = (const unsigned short*)(L + H1B_F);
    _Float16* W2H = (_Float16*)(L + WT_F);
    int* OFF = (int*)(L + OFF_F);
    const int tid = threadIdx.x;
    const int b0 = blockIdx.x * 8;

    // ================= phase A: conv1 + relu + pool -> H1H (f16) ===========
    for (int i = tid; i < 1568; i += 256)
        ((float4*)(L + XS_F))[i] = ((const float4*)(xg + (size_t)b0 * 784))[i];
    if (tid < 150) L[WT_F + (tid % 25) * 8 + tid / 25] = c1w[tid];
    if (tid < 6) L[BS1_F + tid] = c1b[tid];
    __syncthreads();

    for (int t = tid; t < 1152; t += 256) {
        const int s = t / 144;
        const int r = t - s * 144;
        const int py = r / 12, px = r - (r / 12) * 12;
        const float* xp = L + XS_F + s * 784 + (2 * py) * 28 + 2 * px;

        float p[6][6];
#pragma unroll
        for (int rr = 0; rr < 6; rr++) {
            float2 u = *(const float2*)(xp + rr * 28);
            float2 v = *(const float2*)(xp + rr * 28 + 2);
            float2 w = *(const float2*)(xp + rr * 28 + 4);
            p[rr][0] = u.x; p[rr][1] = u.y; p[rr][2] = v.x;
            p[rr][3] = v.y; p[rr][4] = w.x; p[rr][5] = w.y;
        }

        float acc[6][4];
#pragma unroll
        for (int o = 0; o < 6; o++) {
            const float bv = L[BS1_F + o];
            acc[o][0] = bv; acc[o][1] = bv; acc[o][2] = bv; acc[o][3] = bv;
        }

#pragma unroll
        for (int ky = 0; ky < 5; ky++)
#pragma unroll
            for (int kx = 0; kx < 5; kx++) {
                const int k = ky * 5 + kx;
                const float4 wA = *(const float4*)&L[WT_F + k * 8];
                const float2 wB = *(const float2*)&L[WT_F + k * 8 + 4];
                const float p00 = p[ky][kx],     p01 = p[ky][kx + 1];
                const float p10 = p[ky + 1][kx], p11 = p[ky + 1][kx + 1];
                acc[0][0] = fmaf(wA.x, p00, acc[0][0]); acc[0][1] = fmaf(wA.x, p01, acc[0][1]);
                acc[0][2] = fmaf(wA.x, p10, acc[0][2]); acc[0][3] = fmaf(wA.x, p11, acc[0][3]);
                acc[1][0] = fmaf(wA.y, p00, acc[1][0]); acc[1][1] = fmaf(wA.y, p01, acc[1][1]);
                acc[1][2] = fmaf(wA.y, p10, acc[1][2]); acc[1][3] = fmaf(wA.y, p11, acc[1][3]);
                acc[2][0] = fmaf(wA.z, p00, acc[2][0]); acc[2][1] = fmaf(wA.z, p01, acc[2][1]);
                acc[2][2] = fmaf(wA.z, p10, acc[2][2]); acc[2][3] = fmaf(wA.z, p11, acc[2][3]);
                acc[3][0] = fmaf(wA.w, p00, acc[3][0]); acc[3][1] = fmaf(wA.w, p01, acc[3][1]);
                acc[3][2] = fmaf(wA.w, p10, acc[3][2]); acc[3][3] = fmaf(wA.w, p11, acc[3][3]);
                acc[4][0] = fmaf(wB.x, p00, acc[4][0]); acc[4][1] = fmaf(wB.x, p01, acc[4][1]);
                acc[4][2] = fmaf(wB.x, p10, acc[4][2]); acc[4][3] = fmaf(wB.x, p11, acc[4][3]);
                acc[5][0] = fmaf(wB.y, p00, acc[5][0]); acc[5][1] = fmaf(wB.y, p01, acc[5][1]);
                acc[5][2] = fmaf(wB.y, p10, acc[5][2]); acc[5][3] = fmaf(wB.y, p11, acc[5][3]);
            }

        _Float16* op = H1H + s * 864 + py * 12 + px;
#pragma unroll
        for (int o = 0; o < 6; o++) {
            const float m = fmaxf(fmaxf(acc[o][0], acc[o][1]), fmaxf(acc[o][2], acc[o][3]));
            op[o * 144] = (_Float16)fmaxf(m, 0.f);
        }
    }
    __syncthreads();

    // ================= phase B: conv2 via f16 MFMA =========================
    // stage W2H [oc][k] f16 (K padded 150->160 with zeros), OFF table, bias
    for (int i = tid; i < 2400; i += 256) {
        const int n = i / 150, k = i - n * 150;
        W2H[n * 160 + k] = (_Float16)c2w[i];
    }
    if (tid < 160) {
        const int n = tid / 10, kk = tid - n * 10;
        W2H[n * 160 + 150 + kk] = (_Float16)0.f;
    }
    if (tid < 160) {
        int off = 0;
        if (tid < 150) {
            const int ic = tid / 25, t2 = tid - ic * 25;
            const int ky = t2 / 5, kx = t2 - ky * 5;
            off = ic * 144 + ky * 12 + kx;
        }
        OFF[tid] = off;
    }
    if (tid < 16) L[BS2_F + tid] = c2b[tid];
    __syncthreads();

    {
        const int lane = tid & 63;
        const int wvi = tid >> 6;         // wave id; handles samples 2w, 2w+1
        const int ml = lane & 15;         // A row / B col / C col
        const int q = lane >> 4;          // k-group / C row-group
        const int bp = (ml >> 3) * 12 + (ml & 7);  // pos offset for tile 0

        f32x4 c[2][4];
#pragma unroll
        for (int a = 0; a < 2; a++)
#pragma unroll
            for (int b = 0; b < 4; b++) c[a][b] = (f32x4){0.f, 0.f, 0.f, 0.f};

#pragma unroll
        for (int ks = 0; ks < 5; ks++) {
            int o[8];
#pragma unroll
            for (int j = 0; j < 8; j++) o[j] = OFF[ks * 32 + q * 8 + j];
            const half8 bfrag = *(const half8*)&W2H[ml * 160 + ks * 32 + q * 8];
#pragma unroll
            for (int si = 0; si < 2; si++) {
                const unsigned short* hp = H1U + (2 * wvi + si) * 864 + bp;
#pragma unroll
                for (int t = 0; t < 4; t++) {
                    AU au;
#pragma unroll
                    for (int j = 0; j < 4; j++) {
                        const unsigned lo = hp[24 * t + o[2 * j]];
                        const unsigned hi = hp[24 * t + o[2 * j + 1]];
                        au.w[j] = lo | (hi << 16);
                    }
                    c[si][t] = __builtin_amdgcn_mfma_f32_16x16x32_f16(au.h, bfrag, c[si][t], 0, 0, 0);
                }
            }
        }

        // bias + 2x2 pool (x: reg pairs, y: shfl_xor 32) + relu -> H2S fp32
        const float bv = L[BS2_F + ml];
#pragma unroll
        for (int si = 0; si < 2; si++) {
            const int s = 2 * wvi + si;
#pragma unroll
            for (int t = 0; t < 4; t++) {
                const float c0 = c[si][t][0] + bv, c1 = c[si][t][1] + bv;
                const float c2 = c[si][t][2] + bv, c3 = c[si][t][3] + bv;
                float px0 = fmaxf(c0, c1), px1 = fmaxf(c2, c3);
                px0 = fmaxf(px0, __shfl_xor(px0, 32));
                px1 = fmaxf(px1, __shfl_xor(px1, 32));
                if (lane < 32) {
                    float* dst = L + H2S_F + s * 320 + ml * 20 + t * 4 + (q & 1) * 2;
                    dst[0] = fmaxf(px0, 0.f);
                    dst[1] = fmaxf(px1, 0.f);
                }
            }
        }
    }
    __syncthreads();

    // ================= phase C: fc1 (256->120) + relu, fc2 (120->4) ========
    for (int i = tid; i < 480; i += 256) L[FC2W_F + i] = f2w[i];
    if (tid < 4) L[FC2W_F + 480 + tid] = f2b[tid];

    const int g = tid / 120;          // 0,1 active; 2 idle
    const int n = tid - g * 120;
    float facc[4] = {0.f, 0.f, 0.f, 0.f};

    for (int kc = 0; kc < 4; kc++) {
        for (int i = tid; i < 1920; i += 256) {
            const int nn = i >> 4, jj4 = i & 15;
            *(float4*)&L[W1C_F + nn * 68 + jj4 * 4] =
                ((const float4*)(f1w + (size_t)nn * 256 + kc * 64))[jj4];
        }
        __syncthreads();
        if (g < 2) {
#pragma unroll
            for (int j = 0; j < 64; j += 4) {
                const float4 wv = *(const float4*)&L[W1C_F + n * 68 + j];
                const int k = kc * 64 + j;
                const int row = (k >> 4) * 20 + (k & 15);
#pragma unroll
                for (int i = 0; i < 4; i++) {
                    const float4 hv = *(const float4*)&L[H2S_F + (g * 4 + i) * 320 + row];
                    facc[i] = fmaf(wv.x, hv.x, facc[i]);
                    facc[i] = fmaf(wv.y, hv.y, facc[i]);
                    facc[i] = fmaf(wv.z, hv.z, facc[i]);
                    facc[i] = fmaf(wv.w, hv.w, facc[i]);
                }
            }
        }
        __syncthreads();
    }

    if (g < 2) {
        const float bv = f1b[n];
#pragma unroll
        for (int i = 0; i < 4; i++)
            L[HS_F + (g * 4 + i) * 124 + n] = fmaxf(facc[i] + bv, 0.f);
    }
    __syncthreads();

    if (tid < 32) {
        const int s = tid >> 2, m = tid & 3;
        float f = L[FC2W_F + 480 + m];
#pragma unroll
        for (int nn = 0; nn < 120; nn += 4) {
            const float4 wv = *(const float4*)&L[FC2W_F + m * 120 + nn];
            const float4 hv = *(const float4*)&L[HS_F + s * 124 + nn];
            f = fmaf(wv.x, hv.x, f);
            f = fmaf(wv.y, hv.y, f);
            f = fmaf(wv.z, hv.z, f);
            f = fmaf(wv.w, hv.w, f);
        }
        L[ANG_F + s * 4 + m] = 3.14159265358979323846f / (1.f + expf(-f));
    }
    __syncthreads();

    // ================= phase D: quantum circuit + classifier ===============
    if (tid < 8) {
        const int s = tid;
        const float av[4] = {L[ANG_F + s * 4 + 0], L[ANG_F + s * 4 + 1],
                             L[ANG_F + s * 4 + 2], L[ANG_F + s * 4 + 3]};
        float sr[16], si[16];
#pragma unroll
        for (int i = 0; i < 16; i++) { sr[i] = 0.f; si[i] = 0.f; }
        sr[0] = 1.f;

#pragma unroll
        for (int l = 0; l < 3; l++) {
#pragma unroll
            for (int w = 0; w < 4; w++) {
                const float phi = qw[(l * 4 + w) * 3 + 0];
                const float th  = qw[(l * 4 + w) * 3 + 1];
                const float om  = qw[(l * 4 + w) * 3 + 2];
                const float ct = cosf(0.5f * th), st = sinf(0.5f * th);
                const float ap = 0.5f * (phi + om), bm = 0.5f * (phi - om);
                const float ca = cosf(ap), sa = sinf(ap);
                const float cbm = cosf(bm), sbm = sinf(bm);
                const float m00r =  ct * ca,  m00i = -ct * sa;
                const float m01r = -st * cbm, m01i = -st * sbm;
                const float m10r =  st * cbm, m10i = -st * sbm;
                const float m11r =  ct * ca,  m11i =  ct * sa;
                const int mask = 8 >> w;
#pragma unroll
                for (int i = 0; i < 16; i++)
                    if (!(i & mask)) {
                        const int j = i | mask;
                        const float xr = sr[i], xi = si[i], yr = sr[j], yi = si[j];
                        sr[i] = m00r * xr - m00i * xi + m01r * yr - m01i * yi;
                        si[i] = m00r * xi + m00i * xr + m01r * yi + m01i * yr;
                        sr[j] = m10r * xr - m10i * xi + m11r * yr - m11i * yi;
                        si[j] = m10r * xi + m10i * xr + m11r * yi + m11i * yr;
                    }
            }
#pragma unroll
            for (int w = 0; w < 4; w++) {
                const int mc = 8 >> w, mt = 8 >> ((w + 1) & 3);
#pragma unroll
                for (int i = 0; i < 16; i++)
                    if ((i & mc) && !(i & mt)) {
                        const int j = i | mt;
                        const float tr = sr[i], ti = si[i];
                        sr[i] = sr[j]; si[i] = si[j];
                        sr[j] = tr;    si[j] = ti;
                    }
            }
#pragma unroll
            for (int w = 0; w < 4; w++) {
                const float c = cosf(0.5f * av[w]), s2 = sinf(0.5f * av[w]);
                const int mask = 8 >> w;
#pragma unroll
                for (int i = 0; i < 16; i++)
                    if (!(i & mask)) {
                        const int j = i | mask;
                        const float xr = sr[i], xi = si[i], yr = sr[j], yi = si[j];
                        sr[i] = c * xr + s2 * yi;
                        si[i] = c * xi - s2 * yr;
                        sr[j] = c * yr + s2 * xi;
                        si[j] = c * yi - s2 * xr;
                    }
            }
        }

        float z[4];
#pragma unroll
        for (int w = 0; w < 4; w++) {
            const int mask = 8 >> w;
            float zacc = 0.f;
#pragma unroll
            for (int i = 0; i < 16; i++) {
                const float pv = sr[i] * sr[i] + si[i] * si[i];
                zacc += (i & mask) ? -pv : pv;
            }
            z[w] = zacc;
        }
#pragma unroll
        for (int c = 0; c < 10; c++) {
            float v = cbias[c];
#pragma unroll
            for (int w = 0; w < 4; w++) v = fmaf(cw[c * 4 + w], z[w], v);
            out[(size_t)(b0 + s) * 10 + c] = v;
        }
    }
}

// ---------------------------------------------------------------------------
extern "C" void kernel_launch(void* const* d_in, const int* in_sizes, int n_in,
                              void* d_out, int out_size, void* d_ws, size_t ws_size,
                              hipStream_t stream) {
    const float* x   = (const float*)d_in[0];
    const float* c1w = (const float*)d_in[1];
    const float* c1b = (const float*)d_in[2];
    const float* c2w = (const float*)d_in[3];
    const float* c2b = (const float*)d_in[4];
    const float* f1w = (const float*)d_in[5];
    const float* f1b = (const float*)d_in[6];
    const float* f2w = (const float*)d_in[7];
    const float* f2b = (const float*)d_in[8];
    const float* qw  = (const float*)d_in[9];
    const float* cw  = (const float*)d_in[10];
    const float* cb  = (const float*)d_in[11];
    float* out = (float*)d_out;

    fused_model<<<BATCH_N / 8, 256, 0, stream>>>(x, c1w, c1b, c2w, c2b,
                                                 f1w, f1b, f2w, f2b,
                                                 qw, cw, cb, out);
}

// Round 7
// 217.172 us; speedup vs baseline: 1.3777x; 1.2353x over previous
//
#include <hip/hip_runtime.h>
#include <math.h>

#define BATCH_N 16384

typedef _Float16 half8 __attribute__((ext_vector_type(8)));
typedef _Float16 half2v __attribute__((ext_vector_type(2)));
typedef float f32x4 __attribute__((ext_vector_type(4)));

// ---------------------------------------------------------------------------
// LDS float-index map (11880 floats = 47520 B -> 3 blocks/CU):
//  [0,200)     C1W   conv1 w transposed [25][8] fp32
//  [200,208)   BS1   conv1 bias
//  [208,224)   BS2   conv2 bias
//  [224,708)   FC2W  fc2 w (480) + b (4)
//  [708,740)   ANG   angles fp32 [8][4]
//  [744,2600)  W2B   conv2 w f16 [16 oc][232]: k' = tap*8+ic (pad ic 6,7=0,
//                    taps 25..28 zero; row stride 232 breaks bank alignment)
//  [2600,3624) H2    h2 f16 [8 s][256]  (k-order oc*16+pooledpos = fc1 k)
//  [3624,4136) HS    fc1 out f16 [8 s][128]
//  [4136,11880) per-wave scratch, 1936 floats each:
//      XW  f16 [2 s][784]   x staging
//      H1C f16 [2 s][144 pix][8]  channel-last pooled conv1 out
// ---------------------------------------------------------------------------
#define C1W_F  0
#define BS1_F  200
#define BS2_F  208
#define FC2W_F 224
#define ANG_F  708
#define W2B_F  744
#define H2_F   2600
#define HS_F   3624
#define PW_F   4136
#define PW_STRIDE 1936
#define LDS_FLOATS 11880

__global__ __launch_bounds__(256, 3) void fused_model(
    const float* __restrict__ xg,
    const float* __restrict__ c1w, const float* __restrict__ c1b,
    const float* __restrict__ c2w, const float* __restrict__ c2b,
    const float* __restrict__ f1w, const float* __restrict__ f1b,
    const float* __restrict__ f2w, const float* __restrict__ f2b,
    const float* __restrict__ qw,  const float* __restrict__ cw,
    const float* __restrict__ cbias, float* __restrict__ out) {
    __shared__ float L[LDS_FLOATS];
    const int tid = threadIdx.x;
    const int b0 = blockIdx.x * 8;
    const int lane = tid & 63, wvi = tid >> 6;
    const int ml = lane & 15, q = lane >> 4;

    _Float16* W2BH = (_Float16*)(L + W2B_F);
    _Float16* H2H  = (_Float16*)(L + H2_F);
    _Float16* HSH  = (_Float16*)(L + HS_F);
    _Float16* XWH  = (_Float16*)(L + PW_F + wvi * PW_STRIDE);
    _Float16* H1CH = XWH + 1568;

    // ================= stage shared weights (one barrier) ==================
    if (tid < 150) L[C1W_F + (tid % 25) * 8 + tid / 25] = c1w[tid];
    if (tid < 6)  L[BS1_F + tid] = c1b[tid];
    if (tid < 16) L[BS2_F + tid] = c2b[tid];
    for (int i = tid; i < 480; i += 256) L[FC2W_F + i] = f2w[i];
    if (tid < 4) L[FC2W_F + 480 + tid] = f2b[tid];
    for (int i = tid; i < 3712; i += 256) {
        const int oc = i / 232, r = i - oc * 232;
        float v = 0.f;
        if (r < 200) {
            const int pix = r >> 3, ic = r & 7;
            if (ic < 6) v = c2w[oc * 150 + ic * 25 + pix];
        }
        W2BH[oc * 232 + r] = (_Float16)v;
    }
    __syncthreads();

    // ============ per-wave: x -> LDS f16 (2 samples, no barrier) ===========
    {
        const float4* xg4 = (const float4*)(xg + (size_t)(b0 + 2 * wvi) * 784);
        for (int i = lane; i < 392; i += 64) {
            const float4 v = xg4[i];
            union { _Float16 h[4]; uint2 u; } P;
            P.h[0] = (_Float16)v.x; P.h[1] = (_Float16)v.y;
            P.h[2] = (_Float16)v.z; P.h[3] = (_Float16)v.w;
            *(uint2*)(XWH + i * 4) = P.u;
        }
    }
    __builtin_amdgcn_wave_barrier();

    // ============ per-wave conv1 + relu + pool -> H1C (channel-last) =======
    for (int t = lane; t < 288; t += 64) {
        const int s = t >= 144 ? 1 : 0;
        const int r = t - s * 144;
        const int py = r / 12, px = r - (r / 12) * 12;
        const _Float16* xp = XWH + s * 784 + (2 * py) * 28 + 2 * px;

        float p[6][6];
#pragma unroll
        for (int rr = 0; rr < 6; rr++) {
            const half2v a = *(const half2v*)(xp + rr * 28);
            const half2v b = *(const half2v*)(xp + rr * 28 + 2);
            const half2v c = *(const half2v*)(xp + rr * 28 + 4);
            p[rr][0] = (float)a[0]; p[rr][1] = (float)a[1];
            p[rr][2] = (float)b[0]; p[rr][3] = (float)b[1];
            p[rr][4] = (float)c[0]; p[rr][5] = (float)c[1];
        }

        float acc[6][4];
#pragma unroll
        for (int o = 0; o < 6; o++) {
            const float bv = L[BS1_F + o];
            acc[o][0] = bv; acc[o][1] = bv; acc[o][2] = bv; acc[o][3] = bv;
        }
#pragma unroll
        for (int ky = 0; ky < 5; ky++)
#pragma unroll
            for (int kx = 0; kx < 5; kx++) {
                const int k = ky * 5 + kx;
                const float4 wA = *(const float4*)&L[C1W_F + k * 8];
                const float2 wB = *(const float2*)&L[C1W_F + k * 8 + 4];
                const float p00 = p[ky][kx],     p01 = p[ky][kx + 1];
                const float p10 = p[ky + 1][kx], p11 = p[ky + 1][kx + 1];
                acc[0][0] = fmaf(wA.x, p00, acc[0][0]); acc[0][1] = fmaf(wA.x, p01, acc[0][1]);
                acc[0][2] = fmaf(wA.x, p10, acc[0][2]); acc[0][3] = fmaf(wA.x, p11, acc[0][3]);
                acc[1][0] = fmaf(wA.y, p00, acc[1][0]); acc[1][1] = fmaf(wA.y, p01, acc[1][1]);
                acc[1][2] = fmaf(wA.y, p10, acc[1][2]); acc[1][3] = fmaf(wA.y, p11, acc[1][3]);
                acc[2][0] = fmaf(wA.z, p00, acc[2][0]); acc[2][1] = fmaf(wA.z, p01, acc[2][1]);
                acc[2][2] = fmaf(wA.z, p10, acc[2][2]); acc[2][3] = fmaf(wA.z, p11, acc[2][3]);
                acc[3][0] = fmaf(wA.w, p00, acc[3][0]); acc[3][1] = fmaf(wA.w, p01, acc[3][1]);
                acc[3][2] = fmaf(wA.w, p10, acc[3][2]); acc[3][3] = fmaf(wA.w, p11, acc[3][3]);
                acc[4][0] = fmaf(wB.x, p00, acc[4][0]); acc[4][1] = fmaf(wB.x, p01, acc[4][1]);
                acc[4][2] = fmaf(wB.x, p10, acc[4][2]); acc[4][3] = fmaf(wB.x, p11, acc[4][3]);
                acc[5][0] = fmaf(wB.y, p00, acc[5][0]); acc[5][1] = fmaf(wB.y, p01, acc[5][1]);
                acc[5][2] = fmaf(wB.y, p10, acc[5][2]); acc[5][3] = fmaf(wB.y, p11, acc[5][3]);
            }

        union { _Float16 h[8]; uint4 u; } O;
#pragma unroll
        for (int o = 0; o < 6; o++) {
            const float m = fmaxf(fmaxf(acc[o][0], acc[o][1]), fmaxf(acc[o][2], acc[o][3]));
            O.h[o] = (_Float16)fmaxf(m, 0.f);
        }
        O.h[6] = (_Float16)0.f; O.h[7] = (_Float16)0.f;
        *(uint4*)(H1CH + s * 1152 + (py * 12 + px) * 8) = O.u;
    }
    __builtin_amdgcn_wave_barrier();

    // ============ per-wave conv2 via MFMA (aligned b128 fragments) =========
    {
        f32x4 c2a[2][4];
#pragma unroll
        for (int a = 0; a < 2; a++)
#pragma unroll
            for (int b = 0; b < 4; b++) c2a[a][b] = (f32x4){0.f, 0.f, 0.f, 0.f};

#pragma unroll
        for (int ks = 0; ks < 7; ks++) {
            const half8 bfrag = *(const half8*)(W2BH + ml * 232 + ks * 32 + q * 8);
            int tp = ks * 4 + q; if (tp > 24) tp = 24;  // pad taps: B=0, A junk ok
            const int poff = (tp / 5) * 12 + (tp % 5);
#pragma unroll
            for (int si = 0; si < 2; si++) {
                const _Float16* hp = H1CH + si * 1152;
#pragma unroll
                for (int t = 0; t < 4; t++) {
                    const int cp = t * 16 + ml;
                    const int pix = (cp >> 3) * 12 + (cp & 7) + poff;
                    const half8 afrag = *(const half8*)(hp + pix * 8);
                    c2a[si][t] = __builtin_amdgcn_mfma_f32_16x16x32_f16(afrag, bfrag, c2a[si][t], 0, 0, 0);
                }
            }
        }

        const float bv = L[BS2_F + ml];
#pragma unroll
        for (int si = 0; si < 2; si++) {
#pragma unroll
            for (int t = 0; t < 4; t++) {
                const float c0 = c2a[si][t][0] + bv, c1 = c2a[si][t][1] + bv;
                const float c2 = c2a[si][t][2] + bv, c3 = c2a[si][t][3] + bv;
                float px0 = fmaxf(c0, c1), px1 = fmaxf(c2, c3);
                px0 = fmaxf(px0, __shfl_xor(px0, 32));
                px1 = fmaxf(px1, __shfl_xor(px1, 32));
                if (lane < 32) {
                    union { _Float16 h[2]; unsigned u; } P2;
                    P2.h[0] = (_Float16)fmaxf(px0, 0.f);
                    P2.h[1] = (_Float16)fmaxf(px1, 0.f);
                    *(unsigned*)(H2H + (2 * wvi + si) * 256 + ml * 16 + t * 4 + (q & 1) * 2) = P2.u;
                }
            }
        }
    }
    __syncthreads();

    // ============ fc1 (256->120) via MFMA, M=8 samples =====================
    {
        f32x4 fcC[2];
        fcC[0] = (f32x4){0.f, 0.f, 0.f, 0.f};
        fcC[1] = (f32x4){0.f, 0.f, 0.f, 0.f};
        const int ms = (ml < 8) ? ml : 0;
#pragma unroll
        for (int ks = 0; ks < 8; ks++) {
            const half8 afrag = *(const half8*)(H2H + ms * 256 + ks * 32 + q * 8);
#pragma unroll
            for (int ti = 0; ti < 2; ti++) {
                const int n = (wvi + 4 * ti) * 16 + ml;
                half8 bfrag;
                if (n < 120) {
                    const float* wp = f1w + (size_t)n * 256 + ks * 32 + q * 8;
                    const float4 u = *(const float4*)wp;
                    const float4 v = *(const float4*)(wp + 4);
                    bfrag[0] = (_Float16)u.x; bfrag[1] = (_Float16)u.y;
                    bfrag[2] = (_Float16)u.z; bfrag[3] = (_Float16)u.w;
                    bfrag[4] = (_Float16)v.x; bfrag[5] = (_Float16)v.y;
                    bfrag[6] = (_Float16)v.z; bfrag[7] = (_Float16)v.w;
                } else {
#pragma unroll
                    for (int j = 0; j < 8; j++) bfrag[j] = (_Float16)0.f;
                }
                fcC[ti] = __builtin_amdgcn_mfma_f32_16x16x32_f16(afrag, bfrag, fcC[ti], 0, 0, 0);
            }
        }
        if (q < 2) {
#pragma unroll
            for (int ti = 0; ti < 2; ti++) {
                const int n = (wvi + 4 * ti) * 16 + ml;
                if (n < 120) {
                    const float bb = f1b[n];
#pragma unroll
                    for (int rg = 0; rg < 4; rg++) {
                        const int s = q * 4 + rg;
                        HSH[s * 128 + n] = (_Float16)fmaxf(fcC[ti][rg] + bb, 0.f);
                    }
                }
            }
        }
    }
    __syncthreads();

    // ============ fc2 (120->4) + pi*sigmoid ================================
    if (tid < 32) {
        const int s = tid >> 2, m = tid & 3;
        float f = L[FC2W_F + 480 + m];
        for (int nn = 0; nn < 120; nn += 8) {
            const half8 hv = *(const half8*)(HSH + s * 128 + nn);
            const float* wp = &L[FC2W_F + m * 120 + nn];
            f = fmaf(wp[0], (float)hv[0], f); f = fmaf(wp[1], (float)hv[1], f);
            f = fmaf(wp[2], (float)hv[2], f); f = fmaf(wp[3], (float)hv[3], f);
            f = fmaf(wp[4], (float)hv[4], f); f = fmaf(wp[5], (float)hv[5], f);
            f = fmaf(wp[6], (float)hv[6], f); f = fmaf(wp[7], (float)hv[7], f);
        }
        L[ANG_F + s * 4 + m] = 3.14159265358979323846f / (1.f + expf(-f));
    }
    __syncthreads();

    // ============ quantum circuit + classifier =============================
    if (tid < 8) {
        const int s = tid;
        const float av[4] = {L[ANG_F + s * 4 + 0], L[ANG_F + s * 4 + 1],
                             L[ANG_F + s * 4 + 2], L[ANG_F + s * 4 + 3]};
        float sr[16], si[16];
#pragma unroll
        for (int i = 0; i < 16; i++) { sr[i] = 0.f; si[i] = 0.f; }
        sr[0] = 1.f;

#pragma unroll
        for (int l = 0; l < 3; l++) {
#pragma unroll
            for (int w = 0; w < 4; w++) {
                const float phi = qw[(l * 4 + w) * 3 + 0];
                const float th  = qw[(l * 4 + w) * 3 + 1];
                const float om  = qw[(l * 4 + w) * 3 + 2];
                const float ct = cosf(0.5f * th), st = sinf(0.5f * th);
                const float ap = 0.5f * (phi + om), bm = 0.5f * (phi - om);
                const float ca = cosf(ap), sa = sinf(ap);
                const float cbm = cosf(bm), sbm = sinf(bm);
                const float m00r =  ct * ca,  m00i = -ct * sa;
                const float m01r = -st * cbm, m01i = -st * sbm;
                const float m10r =  st * cbm, m10i = -st * sbm;
                const float m11r =  ct * ca,  m11i =  ct * sa;
                const int mask = 8 >> w;
#pragma unroll
                for (int i = 0; i < 16; i++)
                    if (!(i & mask)) {
                        const int j = i | mask;
                        const float xr = sr[i], xi = si[i], yr = sr[j], yi = si[j];
                        sr[i] = m00r * xr - m00i * xi + m01r * yr - m01i * yi;
                        si[i] = m00r * xi + m00i * xr + m01r * yi + m01i * yr;
                        sr[j] = m10r * xr - m10i * xi + m11r * yr - m11i * yi;
                        si[j] = m10r * xi + m10i * xr + m11r * yi + m11i * yr;
                    }
            }
#pragma unroll
            for (int w = 0; w < 4; w++) {
                const int mc = 8 >> w, mt = 8 >> ((w + 1) & 3);
#pragma unroll
                for (int i = 0; i < 16; i++)
                    if ((i & mc) && !(i & mt)) {
                        const int j = i | mt;
                        const float tr = sr[i], ti = si[i];
                        sr[i] = sr[j]; si[i] = si[j];
                        sr[j] = tr;    si[j] = ti;
                    }
            }
#pragma unroll
            for (int w = 0; w < 4; w++) {
                const float c = cosf(0.5f * av[w]), s2 = sinf(0.5f * av[w]);
                const int mask = 8 >> w;
#pragma unroll
                for (int i = 0; i < 16; i++)
                    if (!(i & mask)) {
                        const int j = i | mask;
                        const float xr = sr[i], xi = si[i], yr = sr[j], yi = si[j];
                        sr[i] = c * xr + s2 * yi;
                        si[i] = c * xi - s2 * yr;
                        sr[j] = c * yr + s2 * xi;
                        si[j] = c * yi - s2 * xr;
                    }
            }
        }

        float z[4];
#pragma unroll
        for (int w = 0; w < 4; w++) {
            const int mask = 8 >> w;
            float zacc = 0.f;
#pragma unroll
            for (int i = 0; i < 16; i++) {
                const float pv = sr[i] * sr[i] + si[i] * si[i];
                zacc += (i & mask) ? -pv : pv;
            }
            z[w] = zacc;
        }
#pragma unroll
        for (int c = 0; c < 10; c++) {
            float v = cbias[c];
#pragma unroll
            for (int w = 0; w < 4; w++) v = fmaf(cw[c * 4 + w], z[w], v);
            out[(size_t)(b0 + s) * 10 + c] = v;
        }
    }
}

// ---------------------------------------------------------------------------
extern "C" void kernel_launch(void* const* d_in, const int* in_sizes, int n_in,
                              void* d_out, int out_size, void* d_ws, size_t ws_size,
                              hipStream_t stream) {
    const float* x   = (const float*)d_in[0];
    const float* c1w = (const float*)d_in[1];
    const float* c1b = (const float*)d_in[2];
    const float* c2w = (const float*)d_in[3];
    const float* c2b = (const float*)d_in[4];
    const float* f1w = (const float*)d_in[5];
    const float* f1b = (const float*)d_in[6];
    const float* f2w = (const float*)d_in[7];
    const float* f2b = (const float*)d_in[8];
    const float* qw  = (const float*)d_in[9];
    const float* cw  = (const float*)d_in[10];
    const float* cb  = (const float*)d_in[11];
    float* out = (float*)d_out;

    fused_model<<<BATCH_N / 8, 256, 0, stream>>>(x, c1w, c1b, c2w, c2b,
                                                 f1w, f1b, f2w, f2b,
                                                 qw, cw, cb, out);
}

// Round 8
// 181.566 us; speedup vs baseline: 1.6479x; 1.1961x over previous
//
#include <hip/hip_runtime.h>
#include <math.h>

#define BATCH_N 16384

typedef _Float16 half8 __attribute__((ext_vector_type(8)));
typedef float f32x4 __attribute__((ext_vector_type(4)));

// ---------------------------------------------------------------------------
// LDS float-index map (9304 floats = 37216 B -> 4 blocks/CU):
//  [0,200)     C1W   conv1 w transposed [25][8] fp32
//  [200,208)   BS1   conv1 bias
//  [208,224)   BS2   conv2 bias
//  [224,708)   FC2W  fc2 w (480) + b (4)
//  [708,804)   ROTM  12 gates x [m00r,m00i,m01r,m01i,m10r,m10i,m11r,m11i]
//  [804,868)   RXCS  rx cos[32] + sin[32]  (index s*4+w)
//  [868,918)   CWB   clf w (40) + b (10)
//  [920,2776)  W2B   conv2 w f16 [16 oc][232], k' = tap*8+ic
//  [2776,3800) H2    h2 f16 [8 s][256]
//  [3800,4312) HS    fc1 out f16 [8 s][128]
//  [4312,9304) per-wave H1C f16: 2 samples x 156 units x 8 halves
//              (unit = py*13+px; stride 13 breaks the bank-alias period)
// ---------------------------------------------------------------------------
#define C1W_F  0
#define BS1_F  200
#define BS2_F  208
#define FC2W_F 224
#define ROTM_F 708
#define RXCS_F 804
#define CWB_F  868
#define W2B_F  920
#define H2_F   2776
#define HS_F   3800
#define PW_F   4312
#define LDS_FLOATS 9304

__global__ __launch_bounds__(256, 4) void fused_model(
    const float* __restrict__ xg,
    const float* __restrict__ c1w, const float* __restrict__ c1b,
    const float* __restrict__ c2w, const float* __restrict__ c2b,
    const float* __restrict__ f1w, const float* __restrict__ f1b,
    const float* __restrict__ f2w, const float* __restrict__ f2b,
    const float* __restrict__ qw,  const float* __restrict__ cw,
    const float* __restrict__ cbias, float* __restrict__ out) {
    __shared__ float L[LDS_FLOATS];
    const int tid = threadIdx.x;
    const int b0 = blockIdx.x * 8;
    const int lane = tid & 63, wvi = tid >> 6;
    const int ml = lane & 15, q = lane >> 4;

    _Float16* W2BH = (_Float16*)(L + W2B_F);
    _Float16* H2H  = (_Float16*)(L + H2_F);
    _Float16* HSH  = (_Float16*)(L + HS_F);
    _Float16* H1CH = (_Float16*)(L + PW_F) + wvi * 2496;

    // ================= stage shared constants (one barrier) ================
    if (tid < 150) L[C1W_F + (tid % 25) * 8 + tid / 25] = c1w[tid];
    if (tid < 6)  L[BS1_F + tid] = c1b[tid];
    if (tid < 16) L[BS2_F + tid] = c2b[tid];
    for (int i = tid; i < 480; i += 256) L[FC2W_F + i] = f2w[i];
    if (tid < 4) L[FC2W_F + 480 + tid] = f2b[tid];
    if (tid < 40) L[CWB_F + tid] = cw[tid];
    if (tid < 10) L[CWB_F + 40 + tid] = cbias[tid];
    if (tid < 12) {  // Rot gate matrices (batch-uniform)
        const float phi = qw[tid * 3 + 0];
        const float th  = qw[tid * 3 + 1];
        const float om  = qw[tid * 3 + 2];
        const float ct = cosf(0.5f * th), st = sinf(0.5f * th);
        const float ap = 0.5f * (phi + om), bm = 0.5f * (phi - om);
        const float ca = cosf(ap), sa = sinf(ap);
        const float cbm = cosf(bm), sbm = sinf(bm);
        float* R = &L[ROTM_F + tid * 8];
        R[0] =  ct * ca;  R[1] = -ct * sa;
        R[2] = -st * cbm; R[3] = -st * sbm;
        R[4] =  st * cbm; R[5] = -st * sbm;
        R[6] =  ct * ca;  R[7] =  ct * sa;
    }
    for (int i = tid; i < 3712; i += 256) {
        const int oc = i / 232, r = i - oc * 232;
        float v = 0.f;
        if (r < 200) {
            const int pix = r >> 3, ic = r & 7;
            if (ic < 6) v = c2w[oc * 150 + ic * 25 + pix];
        }
        W2BH[oc * 232 + r] = (_Float16)v;
    }
    __syncthreads();

    // ============ per-wave conv1 + relu + pool -> H1C (channel-last) =======
    // x read directly from global (fp32, L2/L3 resident)
    for (int t = lane; t < 288; t += 64) {
        const int s = t >= 144 ? 1 : 0;
        const int r = t - s * 144;
        const int py = r / 12, px = r - (r / 12) * 12;
        const float* xp = xg + (size_t)(b0 + 2 * wvi + s) * 784 + (2 * py) * 28 + 2 * px;

        float p[6][6];
#pragma unroll
        for (int rr = 0; rr < 6; rr++) {
            const float2 a = *(const float2*)(xp + rr * 28);
            const float2 b = *(const float2*)(xp + rr * 28 + 2);
            const float2 c = *(const float2*)(xp + rr * 28 + 4);
            p[rr][0] = a.x; p[rr][1] = a.y; p[rr][2] = b.x;
            p[rr][3] = b.y; p[rr][4] = c.x; p[rr][5] = c.y;
        }

        float acc[6][4];
#pragma unroll
        for (int o = 0; o < 6; o++) {
            const float bv = L[BS1_F + o];
            acc[o][0] = bv; acc[o][1] = bv; acc[o][2] = bv; acc[o][3] = bv;
        }
#pragma unroll
        for (int ky = 0; ky < 5; ky++)
#pragma unroll
            for (int kx = 0; kx < 5; kx++) {
                const int k = ky * 5 + kx;
                const float4 wA = *(const float4*)&L[C1W_F + k * 8];
                const float2 wB = *(const float2*)&L[C1W_F + k * 8 + 4];
                const float p00 = p[ky][kx],     p01 = p[ky][kx + 1];
                const float p10 = p[ky + 1][kx], p11 = p[ky + 1][kx + 1];
                acc[0][0] = fmaf(wA.x, p00, acc[0][0]); acc[0][1] = fmaf(wA.x, p01, acc[0][1]);
                acc[0][2] = fmaf(wA.x, p10, acc[0][2]); acc[0][3] = fmaf(wA.x, p11, acc[0][3]);
                acc[1][0] = fmaf(wA.y, p00, acc[1][0]); acc[1][1] = fmaf(wA.y, p01, acc[1][1]);
                acc[1][2] = fmaf(wA.y, p10, acc[1][2]); acc[1][3] = fmaf(wA.y, p11, acc[1][3]);
                acc[2][0] = fmaf(wA.z, p00, acc[2][0]); acc[2][1] = fmaf(wA.z, p01, acc[2][1]);
                acc[2][2] = fmaf(wA.z, p10, acc[2][2]); acc[2][3] = fmaf(wA.z, p11, acc[2][3]);
                acc[3][0] = fmaf(wA.w, p00, acc[3][0]); acc[3][1] = fmaf(wA.w, p01, acc[3][1]);
                acc[3][2] = fmaf(wA.w, p10, acc[3][2]); acc[3][3] = fmaf(wA.w, p11, acc[3][3]);
                acc[4][0] = fmaf(wB.x, p00, acc[4][0]); acc[4][1] = fmaf(wB.x, p01, acc[4][1]);
                acc[4][2] = fmaf(wB.x, p10, acc[4][2]); acc[4][3] = fmaf(wB.x, p11, acc[4][3]);
                acc[5][0] = fmaf(wB.y, p00, acc[5][0]); acc[5][1] = fmaf(wB.y, p01, acc[5][1]);
                acc[5][2] = fmaf(wB.y, p10, acc[5][2]); acc[5][3] = fmaf(wB.y, p11, acc[5][3]);
            }

        union { _Float16 h[8]; uint4 u; } O;
#pragma unroll
        for (int o = 0; o < 6; o++) {
            const float m = fmaxf(fmaxf(acc[o][0], acc[o][1]), fmaxf(acc[o][2], acc[o][3]));
            O.h[o] = (_Float16)fmaxf(m, 0.f);
        }
        O.h[6] = (_Float16)0.f; O.h[7] = (_Float16)0.f;
        *(uint4*)(H1CH + s * 1248 + (py * 13 + px) * 8) = O.u;
    }
    __builtin_amdgcn_wave_barrier();

    // ============ per-wave conv2 via MFMA (b128 fragments) =================
    {
        f32x4 c2a[2][4];
#pragma unroll
        for (int a = 0; a < 2; a++)
#pragma unroll
            for (int b = 0; b < 4; b++) c2a[a][b] = (f32x4){0.f, 0.f, 0.f, 0.f};

#pragma unroll
        for (int ks = 0; ks < 7; ks++) {
            const half8 bfrag = *(const half8*)(W2BH + ml * 232 + ks * 32 + q * 8);
            int tp = ks * 4 + q; if (tp > 24) tp = 24;  // pad taps: B=0
            const int poff = (tp / 5) * 13 + (tp % 5);
#pragma unroll
            for (int si = 0; si < 2; si++) {
                const _Float16* hp = H1CH + si * 1248;
#pragma unroll
                for (int t = 0; t < 4; t++) {
                    const int cp = t * 16 + ml;
                    const int unit = (cp >> 3) * 13 + (cp & 7) + poff;
                    const half8 afrag = *(const half8*)(hp + unit * 8);
                    c2a[si][t] = __builtin_amdgcn_mfma_f32_16x16x32_f16(afrag, bfrag, c2a[si][t], 0, 0, 0);
                }
            }
        }

        const float bv = L[BS2_F + ml];
#pragma unroll
        for (int si = 0; si < 2; si++) {
#pragma unroll
            for (int t = 0; t < 4; t++) {
                const float c0 = c2a[si][t][0] + bv, c1 = c2a[si][t][1] + bv;
                const float c2 = c2a[si][t][2] + bv, c3 = c2a[si][t][3] + bv;
                float px0 = fmaxf(c0, c1), px1 = fmaxf(c2, c3);
                px0 = fmaxf(px0, __shfl_xor(px0, 32));
                px1 = fmaxf(px1, __shfl_xor(px1, 32));
                if (lane < 32) {
                    union { _Float16 h[2]; unsigned u; } P2;
                    P2.h[0] = (_Float16)fmaxf(px0, 0.f);
                    P2.h[1] = (_Float16)fmaxf(px1, 0.f);
                    *(unsigned*)(H2H + (2 * wvi + si) * 256 + ml * 16 + t * 4 + (q & 1) * 2) = P2.u;
                }
            }
        }
    }
    __syncthreads();

    // ============ fc1 (256->120) via MFMA, M=8 samples =====================
    {
        f32x4 fcC[2];
        fcC[0] = (f32x4){0.f, 0.f, 0.f, 0.f};
        fcC[1] = (f32x4){0.f, 0.f, 0.f, 0.f};
        const int ms = (ml < 8) ? ml : 0;
#pragma unroll
        for (int ks = 0; ks < 8; ks++) {
            const half8 afrag = *(const half8*)(H2H + ms * 256 + ks * 32 + q * 8);
#pragma unroll
            for (int ti = 0; ti < 2; ti++) {
                const int n = (wvi + 4 * ti) * 16 + ml;
                half8 bfrag;
                if (n < 120) {
                    const float* wp = f1w + (size_t)n * 256 + ks * 32 + q * 8;
                    const float4 u = *(const float4*)wp;
                    const float4 v = *(const float4*)(wp + 4);
                    bfrag[0] = (_Float16)u.x; bfrag[1] = (_Float16)u.y;
                    bfrag[2] = (_Float16)u.z; bfrag[3] = (_Float16)u.w;
                    bfrag[4] = (_Float16)v.x; bfrag[5] = (_Float16)v.y;
                    bfrag[6] = (_Float16)v.z; bfrag[7] = (_Float16)v.w;
                } else {
#pragma unroll
                    for (int j = 0; j < 8; j++) bfrag[j] = (_Float16)0.f;
                }
                fcC[ti] = __builtin_amdgcn_mfma_f32_16x16x32_f16(afrag, bfrag, fcC[ti], 0, 0, 0);
            }
        }
        if (q < 2) {
#pragma unroll
            for (int ti = 0; ti < 2; ti++) {
                const int n = (wvi + 4 * ti) * 16 + ml;
                if (n < 120) {
                    const float bb = f1b[n];
#pragma unroll
                    for (int rg = 0; rg < 4; rg++) {
                        const int s = q * 4 + rg;
                        HSH[s * 128 + n] = (_Float16)fmaxf(fcC[ti][rg] + bb, 0.f);
                    }
                }
            }
        }
    }
    __syncthreads();

    // ============ fc2 (120->4) + pi*sigmoid -> rx cos/sin ==================
    if (tid < 32) {
        const int s = tid >> 2, m = tid & 3;
        float f = L[FC2W_F + 480 + m];
        for (int nn = 0; nn < 120; nn += 8) {
            const half8 hv = *(const half8*)(HSH + s * 128 + nn);
            const float* wp = &L[FC2W_F + m * 120 + nn];
            f = fmaf(wp[0], (float)hv[0], f); f = fmaf(wp[1], (float)hv[1], f);
            f = fmaf(wp[2], (float)hv[2], f); f = fmaf(wp[3], (float)hv[3], f);
            f = fmaf(wp[4], (float)hv[4], f); f = fmaf(wp[5], (float)hv[5], f);
            f = fmaf(wp[6], (float)hv[6], f); f = fmaf(wp[7], (float)hv[7], f);
        }
        const float ang = 3.14159265358979323846f / (1.f + expf(-f));
        L[RXCS_F + tid]      = cosf(0.5f * ang);
        L[RXCS_F + 32 + tid] = sinf(0.5f * ang);
    }
    __syncthreads();

    // ============ circuit: 8 samples x 16 amplitudes on 2 waves ============
    if (tid < 128) {
        const int s = tid >> 4, a = tid & 15;
        float ar = (a == 0) ? 1.f : 0.f, ai = 0.f;

#pragma unroll
        for (int l = 0; l < 3; l++) {
            // Rot gates (uniform matrices from LDS)
#pragma unroll
            for (int w = 0; w < 4; w++) {
                const float* R = &L[ROTM_F + (l * 4 + w) * 8];
                const int mask = 8 >> w;
                const float pr = __shfl_xor(ar, mask);
                const float pi = __shfl_xor(ai, mask);
                const bool bit = (a & mask) != 0;
                const float lr = bit ? pr : ar, li = bit ? pi : ai;
                const float hr = bit ? ar : pr, hi = bit ? ai : pi;
                const float Ar = bit ? R[4] : R[0], Ai = bit ? R[5] : R[1];
                const float Br = bit ? R[6] : R[2], Bi = bit ? R[7] : R[3];
                ar = Ar * lr - Ai * li + Br * hr - Bi * hi;
                ai = Ar * li + Ai * lr + Br * hi + Bi * hr;
            }
            // CNOT ring
#pragma unroll
            for (int w = 0; w < 4; w++) {
                const int mc = 8 >> w, mt = 8 >> ((w + 1) & 3);
                const float pr = __shfl_xor(ar, mt);
                const float pi = __shfl_xor(ai, mt);
                const bool ctrl = (a & mc) != 0;
                ar = ctrl ? pr : ar;
                ai = ctrl ? pi : ai;
            }
            // RX gates (per-sample cos/sin from LDS; symmetric form)
#pragma unroll
            for (int w = 0; w < 4; w++) {
                const int mask = 8 >> w;
                const float c  = L[RXCS_F + s * 4 + w];
                const float s2 = L[RXCS_F + 32 + s * 4 + w];
                const float pr = __shfl_xor(ar, mask);
                const float pi = __shfl_xor(ai, mask);
                const float nr = fmaf(c, ar, s2 * pi);
                const float ni = fmaf(c, ai, -s2 * pr);
                ar = nr; ai = ni;
            }
        }

        // <Z_w> via signed Walsh butterfly: lane (8>>w) ends with z_w
        float v = ar * ar + ai * ai;
#pragma unroll
        for (int d = 1; d < 16; d <<= 1) {
            const float pv = __shfl_xor(v, d);
            v = (a & d) ? (pv - v) : (v + pv);
        }

        // classifier: lanes a<10 compute logit a
        if (a < 10) {
            const int base = (tid & 63) & ~15;
            float lg = L[CWB_F + 40 + a];
#pragma unroll
            for (int w = 0; w < 4; w++) {
                const float zw = __shfl(v, base | (8 >> w));
                lg = fmaf(L[CWB_F + a * 4 + w], zw, lg);
            }
            out[(size_t)(b0 + s) * 10 + a] = lg;
        }
    }
}

// ---------------------------------------------------------------------------
extern "C" void kernel_launch(void* const* d_in, const int* in_sizes, int n_in,
                              void* d_out, int out_size, void* d_ws, size_t ws_size,
                              hipStream_t stream) {
    const float* x   = (const float*)d_in[0];
    const float* c1w = (const float*)d_in[1];
    const float* c1b = (const float*)d_in[2];
    const float* c2w = (const float*)d_in[3];
    const float* c2b = (const float*)d_in[4];
    const float* f1w = (const float*)d_in[5];
    const float* f1b = (const float*)d_in[6];
    const float* f2w = (const float*)d_in[7];
    const float* f2b = (const float*)d_in[8];
    const float* qw  = (const float*)d_in[9];
    const float* cw  = (const float*)d_in[10];
    const float* cb  = (const float*)d_in[11];
    float* out = (float*)d_out;

    fused_model<<<BATCH_N / 8, 256, 0, stream>>>(x, c1w, c1b, c2w, c2b,
                                                 f1w, f1b, f2w, f2b,
                                                 qw, cw, cb, out);
}